// Round 1
// baseline (3659.632 us; speedup 1.0000x reference)
//
#include <hip/hip_runtime.h>
#include <math.h>

#define Bq_ 4
#define Lq_ 4096
#define Dq_ 2048
#define Mq_ 16384      // B*L
#define NW_ 4096       // 2*DQK  (W_qk cols)
#define DQK_ 2048

// GEMM tiling
#define TM 128         // rows per workgroup
#define TN 64          // paired columns per workgroup (64 Q-cols + 64 K-cols)
#define KS 16          // k-step
#define NTILES (DQK_ / TN)   // 32

// ---------------------------------------------------------------------------
// w[d] = sum_{j<2048} W[d*4096 + j] * s[j]     (w = W_q @ start_key)
__global__ __launch_bounds__(256) void wqs_kernel(const float* __restrict__ W,
                                                  const float* __restrict__ s,
                                                  float* __restrict__ w) {
    int d = blockIdx.x;
    int tid = threadIdx.x;
    float acc = 0.f;
    const float* row = W + (size_t)d * NW_;
    for (int j = tid; j < DQK_; j += 256) acc += row[j] * s[j];
    __shared__ float red[256];
    red[tid] = acc;
    __syncthreads();
    for (int off = 128; off > 0; off >>= 1) {
        if (tid < off) red[tid] += red[tid + off];
        __syncthreads();
    }
    if (tid == 0) w[d] = red[0];
}

// c0[b] = dot(tokens[b,0,:], w)   for b<4 ;  block 4: snorm = ||s||^2
__global__ __launch_bounds__(256) void l0_kernel(const float* __restrict__ tokens,
                                                 const float* __restrict__ s,
                                                 const float* __restrict__ w,
                                                 float* __restrict__ c0,
                                                 float* __restrict__ snorm) {
    int b = blockIdx.x;
    int tid = threadIdx.x;
    float acc = 0.f;
    if (b < Bq_) {
        const float* t = tokens + (size_t)b * Lq_ * Dq_;
        for (int dd = tid; dd < Dq_; dd += 256) acc += t[dd] * w[dd];
    } else {
        for (int j = tid; j < DQK_; j += 256) acc += s[j] * s[j];
    }
    __shared__ float red[256];
    red[tid] = acc;
    __syncthreads();
    for (int off = 128; off > 0; off >>= 1) {
        if (tid < off) red[tid] += red[tid + off];
        __syncthreads();
    }
    if (tid == 0) {
        if (b < Bq_) c0[b] = red[0];
        else snorm[0] = red[0];
    }
}

// ---------------------------------------------------------------------------
// Fused GEMM + reduction.
// Q-tile: rows [r0, r0+TM) cols [c0, c0+TN) of W_q
// K-tile: rows [r0-1, r0+TM-1) cols [c0, c0+TN) of W_k (cols 2048+c0..)
// Per-row partials (per n-tile): pa[r]=||q_r||^2, pb[r]=||k_r||^2, pc[r]=q_r.k_{r-1}
__global__ __launch_bounds__(256) void gemm_kernel(const float* __restrict__ T,
                                                   const float* __restrict__ W,
                                                   float* __restrict__ pa,
                                                   float* __restrict__ pb,
                                                   float* __restrict__ pc) {
    __shared__ float As[KS][TM + 4 + 1];  // 129 used rows (+pad to 133 keeps b128 align via 132? use 132)
    __shared__ float Bqs[KS][TN];
    __shared__ float Bks[KS][TN];

    const int mt = blockIdx.x;      // 0..127
    const int nt = blockIdx.y;      // 0..31
    const int r0 = mt * TM;
    const int c0 = nt * TN;
    const int tid = threadIdx.x;
    const int tx = tid & 15;        // column group
    const int ty = tid >> 4;        // row group (8 rows each)

    float accq[8][4];
    float acck[8][4];
#pragma unroll
    for (int i = 0; i < 8; ++i)
#pragma unroll
        for (int j = 0; j < 4; ++j) { accq[i][j] = 0.f; acck[i][j] = 0.f; }

    for (int k0 = 0; k0 < Dq_; k0 += KS) {
        // Load A tile: 129 rows x 16 k, transposed into As[k][row]
        for (int idx = tid; idx < 129 * 4; idx += 256) {
            int ar = idx >> 2;            // 0..128  -> global row r0-1+ar
            int kk4 = (idx & 3) * 4;      // 0,4,8,12
            int gr = r0 - 1 + ar;
            float4 v = make_float4(0.f, 0.f, 0.f, 0.f);
            if (gr >= 0) v = *(const float4*)&T[(size_t)gr * Dq_ + k0 + kk4];
            As[kk4 + 0][ar] = v.x;
            As[kk4 + 1][ar] = v.y;
            As[kk4 + 2][ar] = v.z;
            As[kk4 + 3][ar] = v.w;
        }
        // Load B tiles: 16 k-rows x (64 Q cols + 64 K cols)
        for (int idx = tid; idx < 512; idx += 256) {
            int kk = idx >> 5;            // 0..15
            int j4 = (idx & 31) * 4;      // 0..124
            const float* wrow = &W[(size_t)(k0 + kk) * NW_];
            if (j4 < 64) {
                float4 v = *(const float4*)&wrow[c0 + j4];
                *(float4*)&Bqs[kk][j4] = v;
            } else {
                float4 v = *(const float4*)&wrow[DQK_ + c0 + (j4 - 64)];
                *(float4*)&Bks[kk][j4 - 64] = v;
            }
        }
        __syncthreads();

#pragma unroll
        for (int kk = 0; kk < KS; ++kk) {
            float av[9];
            float4 a0 = *(const float4*)&As[kk][ty * 8];
            float4 a1 = *(const float4*)&As[kk][ty * 8 + 4];
            float a8 = As[kk][ty * 8 + 8];
            av[0] = a0.x; av[1] = a0.y; av[2] = a0.z; av[3] = a0.w;
            av[4] = a1.x; av[5] = a1.y; av[6] = a1.z; av[7] = a1.w;
            av[8] = a8;
            float4 bq = *(const float4*)&Bqs[kk][tx * 4];
            float4 bk = *(const float4*)&Bks[kk][tx * 4];
#pragma unroll
            for (int i = 0; i < 8; ++i) {
                float aq = av[i + 1];   // global row r0 + ty*8 + i
                float ak = av[i];       // global row r0 + ty*8 + i - 1
                accq[i][0] = fmaf(aq, bq.x, accq[i][0]);
                accq[i][1] = fmaf(aq, bq.y, accq[i][1]);
                accq[i][2] = fmaf(aq, bq.z, accq[i][2]);
                accq[i][3] = fmaf(aq, bq.w, accq[i][3]);
                acck[i][0] = fmaf(ak, bk.x, acck[i][0]);
                acck[i][1] = fmaf(ak, bk.y, acck[i][1]);
                acck[i][2] = fmaf(ak, bk.z, acck[i][2]);
                acck[i][3] = fmaf(ak, bk.w, acck[i][3]);
            }
        }
        __syncthreads();
    }

    // Epilogue: per-row reductions across the 16 tx lanes (same ty share rows)
    size_t o = (size_t)nt * Mq_;
#pragma unroll
    for (int i = 0; i < 8; ++i) {
        float sq = 0.f, sk = 0.f, sc = 0.f;
#pragma unroll
        for (int j = 0; j < 4; ++j) {
            float q = accq[i][j], k = acck[i][j];
            sq = fmaf(q, q, sq);
            sk = fmaf(k, k, sk);
            sc = fmaf(q, k, sc);
        }
        for (int m = 1; m < 16; m <<= 1) {
            sq += __shfl_xor(sq, m);
            sk += __shfl_xor(sk, m);
            sc += __shfl_xor(sc, m);
        }
        if (tx == 0) {
            int r = r0 + ty * 8 + i;
            pa[o + r] = sq;                 // ||q_r||^2 partial
            pc[o + r] = sc;                 // q_r . k_{r-1} partial
            if (r > 0) pb[o + r - 1] = sk;  // ||k_{r-1}||^2 partial
        }
    }
}

// ---------------------------------------------------------------------------
// Reduce partials -> probs per row
__global__ __launch_bounds__(256) void rowstat_kernel(const float* __restrict__ pa,
                                                      const float* __restrict__ pb,
                                                      const float* __restrict__ pc,
                                                      const float* __restrict__ c0,
                                                      const float* __restrict__ snorm,
                                                      float* __restrict__ probs) {
    int r = blockIdx.x * 256 + threadIdx.x;   // 0..16383
    float a = 0.f, bb = 0.f, c = 0.f;
    bool first = ((r & (Lq_ - 1)) == 0);
    for (int nt = 0; nt < NTILES; ++nt) {
        size_t o = (size_t)nt * Mq_;
        a += pa[o + r];
        c += pc[o + r];
        if (!first) bb += pb[o + r - 1];
    }
    if (first) { c = c0[r >> 12]; bb = snorm[0]; }
    float na = fmaxf(sqrtf(a), 1e-8f);
    float nb = fmaxf(sqrtf(bb), 1e-8f);
    float cosv = c / (na * nb);
    probs[r] = (1.f - cosv) * 0.5f;
}

// ---------------------------------------------------------------------------
// Per-batch boundary pack: positions, packed probs, chunk ids, counts. aux=0.
__global__ __launch_bounds__(256) void pack_kernel(const float* __restrict__ probs,
                                                   int* __restrict__ posArr,
                                                   float* __restrict__ pprob,
                                                   int* __restrict__ cid,
                                                   int* __restrict__ nch,
                                                   float* __restrict__ aux) {
    int b = blockIdx.x;
    int tid = threadIdx.x;
    int base = b * Lq_ + tid * 16;
    float p[16];
    bool bd[16];
    int c = 0;
#pragma unroll
    for (int u = 0; u < 16; ++u) {
        p[u] = probs[base + u];
        bd[u] = (p[u] > 0.5f) || (tid == 0 && u == 0);
        c += bd[u] ? 1 : 0;
    }
    __shared__ int sc[256];
    sc[tid] = c;
    __syncthreads();
    for (int off = 1; off < 256; off <<= 1) {
        int t = (tid >= off) ? sc[tid - off] : 0;
        __syncthreads();
        sc[tid] += t;
        __syncthreads();
    }
    int idx = sc[tid] - c;   // exclusive prefix
#pragma unroll
    for (int u = 0; u < 16; ++u) {
        if (bd[u]) {
            posArr[b * Lq_ + idx] = tid * 16 + u;
            pprob[b * Lq_ + idx] = p[u];
            idx++;
        }
        cid[base + u] = idx - 1;
    }
    if (tid == 255) nch[b] = sc[255];
    if (b == 0 && tid == 0) aux[0] = 0.0f;
}

// ---------------------------------------------------------------------------
// Gated scan over packed chunks; writes smoothed (tail rows carry last h).
__global__ __launch_bounds__(256) void scan_kernel(const float* __restrict__ tokens,
                                                   const int* __restrict__ posArr,
                                                   const float* __restrict__ pprob,
                                                   const int* __restrict__ nch,
                                                   float* __restrict__ out_sm) {
    int b = blockIdx.y;
    int ch = blockIdx.x * 256 + threadIdx.x;
    int nc = nch[b];
    __shared__ int lpos[Lq_ / 4 * 0 + 4096];
    __shared__ float lpp[4096];
    for (int i = threadIdx.x; i < Lq_; i += 256) {
        lpos[i] = posArr[b * Lq_ + i];
        lpp[i] = pprob[b * Lq_ + i];
    }
    __syncthreads();

    const float* tb = tokens + (size_t)b * Lq_ * Dq_ + ch;
    float* sm = out_sm + (size_t)b * Lq_ * Dq_ + ch;
    float h = 0.f;
    int c = 0;
    for (; c < nc; ++c) {
        float pv = lpp[c];
        int t0 = lpos[c];
        float x = tb[(size_t)t0 * Dq_] * pv;
        h = fmaf(1.f - pv, h, x);
        sm[(size_t)c * Dq_] = h;
    }
    for (; c < Lq_; ++c) sm[(size_t)c * Dq_] = h;
}

// ---------------------------------------------------------------------------
// upsampled[r,:] = smoothed[b, cid[r], :]
__global__ __launch_bounds__(256) void upsample_kernel(const float* __restrict__ sm,
                                                       const int* __restrict__ cid,
                                                       float* __restrict__ up) {
    int r = blockIdx.x;            // 0..16383
    int b = r >> 12;
    int c = cid[r];
    const float* src = sm + ((size_t)b * Lq_ + c) * Dq_;
    float* dst = up + (size_t)r * Dq_;
    int tid = threadIdx.x;
    *(float4*)&dst[tid * 8] = *(const float4*)&src[tid * 8];
    *(float4*)&dst[tid * 8 + 4] = *(const float4*)&src[tid * 8 + 4];
}

// ---------------------------------------------------------------------------
extern "C" void kernel_launch(void* const* d_in, const int* in_sizes, int n_in,
                              void* d_out, int out_size, void* d_ws, size_t ws_size,
                              hipStream_t stream) {
    const float* tokens = (const float*)d_in[0];  // [4,4096,2048]
    const float* W = (const float*)d_in[1];       // [2048,4096]
    const float* s = (const float*)d_in[2];       // [2048]

    float* out = (float*)d_out;
    float* out_sm = out;                          // [4,4096,2048]
    float* out_up = out + (size_t)Mq_ * Dq_;      // [4,4096,2048]
    float* out_aux = out + 2 * (size_t)Mq_ * Dq_; // [1]

    // workspace layout (floats)
    float* ws = (float*)d_ws;
    float* pa = ws;                         // 32*16384
    float* pb = pa + (size_t)NTILES * Mq_;
    float* pc = pb + (size_t)NTILES * Mq_;
    float* probs = pc + (size_t)NTILES * Mq_;   // 16384
    float* w = probs + Mq_;                     // 2048
    float* c0 = w + DQK_;                       // 4
    float* snorm = c0 + 4;                      // 1 (+3 pad)
    float* pprob = snorm + 4;                   // 16384
    int* posArr = (int*)(pprob + Mq_);          // 16384
    int* cid = posArr + Mq_;                    // 16384
    int* nch = cid + Mq_;                       // 4

    wqs_kernel<<<DQK_, 256, 0, stream>>>(W, s, w);
    l0_kernel<<<Bq_ + 1, 256, 0, stream>>>(tokens, s, w, c0, snorm);
    gemm_kernel<<<dim3(Mq_ / TM, NTILES), 256, 0, stream>>>(tokens, W, pa, pb, pc);
    rowstat_kernel<<<Mq_ / 256, 256, 0, stream>>>(pa, pb, pc, c0, snorm, probs);
    pack_kernel<<<Bq_, 256, 0, stream>>>(probs, posArr, pprob, cid, nch, out_aux);
    scan_kernel<<<dim3(Dq_ / 256, Bq_), 256, 0, stream>>>(tokens, posArr, pprob, nch, out_sm);
    upsample_kernel<<<Mq_, 256, 0, stream>>>(out_sm, cid, out_up);
}

// Round 2
// 1004.875 us; speedup vs baseline: 3.6419x; 3.6419x over previous
//
#include <hip/hip_runtime.h>
#include <math.h>

#define Bq_ 4
#define Lq_ 4096
#define Dq_ 2048
#define Mq_ 16384
#define NW_ 4096
#define DQK_ 2048
#define NTILES 32
#define BM_ 128
#define BN_ 64
#define BK_ 64
#define NSEG 16
#define SEGLEN 256

typedef short s8v __attribute__((ext_vector_type(8)));
typedef float f4v __attribute__((ext_vector_type(4)));

#define GLDS16(g, l) __builtin_amdgcn_global_load_lds( \
    (const __attribute__((address_space(1))) unsigned int*)(g), \
    (__attribute__((address_space(3))) unsigned int*)(l), 16, 0, 0)

__device__ __forceinline__ void bf16split(float x, unsigned short& h, unsigned short& l) {
    unsigned u = __float_as_uint(x);
    unsigned hb = (u + 0x7FFFu + ((u >> 16) & 1u)) & 0xFFFF0000u;
    float fh = __uint_as_float(hb);
    float r = x - fh;
    unsigned ur = __float_as_uint(r);
    unsigned lb = (ur + 0x7FFFu + ((ur >> 16) & 1u)) >> 16;
    h = (unsigned short)(hb >> 16);
    l = (unsigned short)lb;
}

// ---------------------------------------------------------------------------
__global__ __launch_bounds__(256) void split_kernel(const float* __restrict__ in,
                                                    unsigned short* __restrict__ hi,
                                                    unsigned short* __restrict__ lo,
                                                    int n4) {
    int stride = gridDim.x * 256;
    for (int i = blockIdx.x * 256 + threadIdx.x; i < n4; i += stride) {
        float4 v = ((const float4*)in)[i];
        float vv[4] = {v.x, v.y, v.z, v.w};
        unsigned short hh[4], ll[4];
#pragma unroll
        for (int j = 0; j < 4; ++j) bf16split(vv[j], hh[j], ll[j]);
        ushort4 h4 = make_ushort4(hh[0], hh[1], hh[2], hh[3]);
        ushort4 l4 = make_ushort4(ll[0], ll[1], ll[2], ll[3]);
        ((ushort4*)hi)[i] = h4;
        ((ushort4*)lo)[i] = l4;
    }
}

// W [2048][4096] f32 -> WhiT/WloT [4096][2048] bf16 (transposed + split)
__global__ __launch_bounds__(256) void wsplitT_kernel(const float* __restrict__ W,
                                                      unsigned short* __restrict__ hiT,
                                                      unsigned short* __restrict__ loT) {
    __shared__ float tile[64][65];
    int k0 = blockIdx.x * 64, n0 = blockIdx.y * 64;
    int tid = threadIdx.x;
#pragma unroll
    for (int e = 0; e < 16; ++e) {
        int idx = e * 256 + tid;
        int r = idx >> 6, j = idx & 63;
        tile[r][j] = W[(size_t)(k0 + r) * NW_ + n0 + j];
    }
    __syncthreads();
#pragma unroll
    for (int e = 0; e < 16; ++e) {
        int idx = e * 256 + tid;
        int nn = idx >> 6, kk = idx & 63;
        unsigned short h, l;
        bf16split(tile[kk][nn], h, l);
        size_t o = (size_t)(n0 + nn) * DQK_ + k0 + kk;
        hiT[o] = h;
        loT[o] = l;
    }
}

// ---------------------------------------------------------------------------
__global__ __launch_bounds__(256) void wqs_kernel(const float* __restrict__ W,
                                                  const float* __restrict__ s,
                                                  float* __restrict__ w) {
    int d = blockIdx.x;
    int tid = threadIdx.x;
    float acc = 0.f;
    const float* row = W + (size_t)d * NW_;
    for (int j = tid; j < DQK_; j += 256) acc += row[j] * s[j];
    __shared__ float red[256];
    red[tid] = acc;
    __syncthreads();
    for (int off = 128; off > 0; off >>= 1) {
        if (tid < off) red[tid] += red[tid + off];
        __syncthreads();
    }
    if (tid == 0) w[d] = red[0];
}

__global__ __launch_bounds__(256) void l0_kernel(const float* __restrict__ tokens,
                                                 const float* __restrict__ s,
                                                 const float* __restrict__ w,
                                                 float* __restrict__ c0,
                                                 float* __restrict__ snorm) {
    int b = blockIdx.x;
    int tid = threadIdx.x;
    float acc = 0.f;
    if (b < Bq_) {
        const float* t = tokens + (size_t)b * Lq_ * Dq_;
        for (int dd = tid; dd < Dq_; dd += 256) acc += t[dd] * w[dd];
    } else {
        for (int jj = tid; jj < DQK_; jj += 256) acc += s[jj] * s[jj];
    }
    __shared__ float red[256];
    red[tid] = acc;
    __syncthreads();
    for (int off = 128; off > 0; off >>= 1) {
        if (tid < off) red[tid] += red[tid + off];
        __syncthreads();
    }
    if (tid == 0) {
        if (b < Bq_) c0[b] = red[0];
        else snorm[0] = red[0];
    }
}

// ---------------------------------------------------------------------------
// bf16x3 MFMA GEMM fused with per-row reductions.
// LDS: A_hi[160][64bf16], A_lo, B_hi[128][64], B_lo  (XOR chunk-swizzled rows)
__global__ __launch_bounds__(256, 2) void gemm_kernel(const unsigned short* __restrict__ Thi,
                                                      const unsigned short* __restrict__ Tlo,
                                                      const unsigned short* __restrict__ Whi,
                                                      const unsigned short* __restrict__ Wlo,
                                                      float* __restrict__ pa,
                                                      float* __restrict__ pkn,
                                                      float* __restrict__ pcn) {
    extern __shared__ char smc[];
    const int AHI = 0, ALO = 20480, BHI = 40960, BLO = 57344;

    int id = blockIdx.x;
    int xc = id >> 9;
    int jj0 = id & 511;
    int mt = jj0 >> 2;
    int nt = (xc << 2) | (jj0 & 3);
    int r0 = mt * BM_;
    int c0 = nt * BN_;
    int tid = threadIdx.x;
    int lane = tid & 63, w = tid >> 6;
    int lr = lane & 15, lg = lane >> 4;

    // staging address precompute: lane covers (row rl, chunk tid&7); swizzled src chunk
    int rl = tid >> 3;
    int swz = ((tid & 7) ^ (rl & 7)) * 8;
    int aoff[5], boff[4];
#pragma unroll
    for (int i = 0; i < 5; ++i) {
        int g = r0 - 1 + i * 32 + rl;
        g = g < 0 ? 0 : (g > Mq_ - 1 ? Mq_ - 1 : g);
        aoff[i] = g * Dq_ + swz;
    }
#pragma unroll
    for (int i = 0; i < 4; ++i) {
        int rowl = i * 32 + rl;
        int wr = rowl < 64 ? c0 + rowl : DQK_ + c0 + (rowl - 64);
        boff[i] = wr * DQK_ + swz;
    }

    // ds read byte-offsets (within each array)
    int aq_ad[2][2], ak_ad[2][2], bq_ad[4][2];
#pragma unroll
    for (int rf = 0; rf < 2; ++rf) {
        int rq = w * 32 + rf * 16 + lr + 1;
        int rk = rq - 1;
#pragma unroll
        for (int s = 0; s < 2; ++s) {
            aq_ad[rf][s] = rq * 128 + (((s * 4 + lg) ^ (rq & 7)) * 16);
            ak_ad[rf][s] = rk * 128 + (((s * 4 + lg) ^ (rk & 7)) * 16);
        }
    }
#pragma unroll
    for (int cf = 0; cf < 4; ++cf) {
        int rb = cf * 16 + lr;
#pragma unroll
        for (int s = 0; s < 2; ++s)
            bq_ad[cf][s] = rb * 128 + (((s * 4 + lg) ^ (rb & 7)) * 16);
    }

    f4v accq[2][4], acck[2][4];
#pragma unroll
    for (int rf = 0; rf < 2; ++rf)
#pragma unroll
        for (int cf = 0; cf < 4; ++cf) {
            accq[rf][cf] = (f4v){0.f, 0.f, 0.f, 0.f};
            acck[rf][cf] = (f4v){0.f, 0.f, 0.f, 0.f};
        }

    for (int kt = 0; kt < 32; ++kt) {
        int k0e = kt * BK_;
#pragma unroll
        for (int i = 0; i < 5; ++i) {
            int ldso = (i * 32 + w * 8) * 128;
            GLDS16(Thi + aoff[i] + k0e, smc + AHI + ldso);
            GLDS16(Tlo + aoff[i] + k0e, smc + ALO + ldso);
        }
#pragma unroll
        for (int i = 0; i < 4; ++i) {
            int ldso = (i * 32 + w * 8) * 128;
            GLDS16(Whi + boff[i] + k0e, smc + BHI + ldso);
            GLDS16(Wlo + boff[i] + k0e, smc + BLO + ldso);
        }
        __syncthreads();
#pragma unroll
        for (int s = 0; s < 2; ++s) {
            s8v aqh[2], aql[2], akh[2], akl[2];
#pragma unroll
            for (int rf = 0; rf < 2; ++rf) {
                aqh[rf] = *(const s8v*)(smc + AHI + aq_ad[rf][s]);
                aql[rf] = *(const s8v*)(smc + ALO + aq_ad[rf][s]);
                akh[rf] = *(const s8v*)(smc + AHI + ak_ad[rf][s]);
                akl[rf] = *(const s8v*)(smc + ALO + ak_ad[rf][s]);
            }
            s8v bqh[4], bql[4], bkh[4], bkl[4];
#pragma unroll
            for (int cf = 0; cf < 4; ++cf) {
                bqh[cf] = *(const s8v*)(smc + BHI + bq_ad[cf][s]);
                bql[cf] = *(const s8v*)(smc + BLO + bq_ad[cf][s]);
                bkh[cf] = *(const s8v*)(smc + BHI + 8192 + bq_ad[cf][s]);
                bkl[cf] = *(const s8v*)(smc + BLO + 8192 + bq_ad[cf][s]);
            }
#pragma unroll
            for (int rf = 0; rf < 2; ++rf)
#pragma unroll
                for (int cf = 0; cf < 4; ++cf) {
                    accq[rf][cf] = __builtin_amdgcn_mfma_f32_16x16x32_bf16(aqh[rf], bqh[cf], accq[rf][cf], 0, 0, 0);
                    accq[rf][cf] = __builtin_amdgcn_mfma_f32_16x16x32_bf16(aqh[rf], bql[cf], accq[rf][cf], 0, 0, 0);
                    accq[rf][cf] = __builtin_amdgcn_mfma_f32_16x16x32_bf16(aql[rf], bqh[cf], accq[rf][cf], 0, 0, 0);
                    acck[rf][cf] = __builtin_amdgcn_mfma_f32_16x16x32_bf16(akh[rf], bkh[cf], acck[rf][cf], 0, 0, 0);
                    acck[rf][cf] = __builtin_amdgcn_mfma_f32_16x16x32_bf16(akh[rf], bkl[cf], acck[rf][cf], 0, 0, 0);
                    acck[rf][cf] = __builtin_amdgcn_mfma_f32_16x16x32_bf16(akl[rf], bkh[cf], acck[rf][cf], 0, 0, 0);
                }
        }
        __syncthreads();
    }

    size_t o = (size_t)nt * Mq_;
#pragma unroll
    for (int rf = 0; rf < 2; ++rf) {
        int rbase = r0 + w * 32 + rf * 16 + lg * 4;
#pragma unroll
        for (int jj = 0; jj < 4; ++jj) {
            float sq = 0.f, sk = 0.f, sc = 0.f;
#pragma unroll
            for (int cf = 0; cf < 4; ++cf) {
                float q = accq[rf][cf][jj];
                float k = acck[rf][cf][jj];
                sq = fmaf(q, q, sq);
                sk = fmaf(k, k, sk);
                sc = fmaf(q, k, sc);
            }
#pragma unroll
            for (int m = 1; m < 16; m <<= 1) {
                sq += __shfl_xor(sq, m);
                sk += __shfl_xor(sk, m);
                sc += __shfl_xor(sc, m);
            }
            if (lr == 0) {
                int r = rbase + jj;
                pa[o + r] = sq;   // ||q_r||^2 partial
                pcn[o + r] = sc;  // q_r . k_{r-1} partial
                pkn[o + r] = sk;  // ||k_{r-1}||^2 partial
            }
        }
    }
}

// ---------------------------------------------------------------------------
__global__ __launch_bounds__(256) void rowstat_kernel(const float* __restrict__ pa,
                                                      const float* __restrict__ pkn,
                                                      const float* __restrict__ pcn,
                                                      const float* __restrict__ c0,
                                                      const float* __restrict__ snorm,
                                                      float* __restrict__ probs) {
    int r = blockIdx.x * 256 + threadIdx.x;
    float a = 0.f, bb = 0.f, c = 0.f;
    for (int nt = 0; nt < NTILES; ++nt) {
        size_t o = (size_t)nt * Mq_;
        a += pa[o + r];
        c += pcn[o + r];
        bb += pkn[o + r];
    }
    if ((r & (Lq_ - 1)) == 0) { c = c0[r >> 12]; bb = snorm[0]; }
    float na = fmaxf(sqrtf(a), 1e-8f);
    float nb = fmaxf(sqrtf(bb), 1e-8f);
    float cosv = c / (na * nb);
    probs[r] = (1.f - cosv) * 0.5f;
}

// ---------------------------------------------------------------------------
__global__ __launch_bounds__(256) void pack_kernel(const float* __restrict__ probs,
                                                   int* __restrict__ posArr,
                                                   float* __restrict__ pprob,
                                                   int* __restrict__ cid,
                                                   int* __restrict__ nch,
                                                   float* __restrict__ aux) {
    int b = blockIdx.x;
    int tid = threadIdx.x;
    int base = b * Lq_ + tid * 16;
#pragma unroll
    for (int u = 0; u < 16; ++u) {
        posArr[base + u] = 0;
        pprob[base + u] = 0.f;
    }
    float p[16];
    bool bd[16];
    int c = 0;
#pragma unroll
    for (int u = 0; u < 16; ++u) {
        p[u] = probs[base + u];
        bd[u] = (p[u] > 0.5f) || (tid == 0 && u == 0);
        c += bd[u] ? 1 : 0;
    }
    __shared__ int sc[256];
    sc[tid] = c;
    __syncthreads();
    for (int off = 1; off < 256; off <<= 1) {
        int t = (tid >= off) ? sc[tid - off] : 0;
        __syncthreads();
        sc[tid] += t;
        __syncthreads();
    }
    int idx = sc[tid] - c;
#pragma unroll
    for (int u = 0; u < 16; ++u) {
        if (bd[u]) {
            posArr[b * Lq_ + idx] = tid * 16 + u;
            pprob[b * Lq_ + idx] = p[u];
            idx++;
        }
        cid[base + u] = idx - 1;
    }
    if (tid == 255) nch[b] = sc[255];
    if (b == 0 && tid == 0) aux[0] = 0.0f;
}

// ---------------------------------------------------------------------------
// Segmented gated scan, pass 1: per-segment end state + segment gate product
__global__ __launch_bounds__(256) void segend_kernel(const float* __restrict__ tokens,
                                                     const int* __restrict__ posArr,
                                                     const float* __restrict__ pprob,
                                                     float* __restrict__ hseg,
                                                     float* __restrict__ segGate) {
    int b = blockIdx.z, s = blockIdx.y;
    int ch = blockIdx.x * 256 + threadIdx.x;
    const float* tb = tokens + (size_t)b * Lq_ * Dq_ + ch;
    const int* pos = posArr + b * Lq_ + s * SEGLEN;
    const float* pp = pprob + b * Lq_ + s * SEGLEN;
    float h = 0.f;
    for (int u = 0; u < SEGLEN; ++u) {
        float pv = pp[u];
        int t0 = pos[u];
        h = fmaf(1.f - pv, h, tb[(size_t)t0 * Dq_] * pv);
    }
    hseg[((size_t)b * NSEG + s) * Dq_ + ch] = h;
    __shared__ float g_[256];
    if (blockIdx.x == 0) {
        g_[threadIdx.x] = 1.f - pp[threadIdx.x];
        __syncthreads();
        if (threadIdx.x == 0) {
            float P = 1.f;
            for (int i = 0; i < 256; ++i) P *= g_[i];
            segGate[b * NSEG + s] = P;
        }
    }
}

// pass 2: sequential carry combine across segments
__global__ __launch_bounds__(256) void carry_kernel(const float* __restrict__ hseg,
                                                    const float* __restrict__ segGate,
                                                    float* __restrict__ carryArr) {
    int idx = blockIdx.x * 256 + threadIdx.x;  // 0..8191
    int b = idx >> 11;
    int ch = idx & 2047;
    float carry = 0.f;
#pragma unroll
    for (int s = 0; s < NSEG; ++s) {
        size_t o = ((size_t)b * NSEG + s) * Dq_ + ch;
        carryArr[o] = carry;
        carry = hseg[o] + carry * segGate[b * NSEG + s];
    }
}

// pass 3: re-scan with carry-in, write smoothed
__global__ __launch_bounds__(256) void scan3_kernel(const float* __restrict__ tokens,
                                                    const int* __restrict__ posArr,
                                                    const float* __restrict__ pprob,
                                                    const float* __restrict__ carryArr,
                                                    float* __restrict__ out_sm) {
    int b = blockIdx.z, s = blockIdx.y;
    int ch = blockIdx.x * 256 + threadIdx.x;
    const float* tb = tokens + (size_t)b * Lq_ * Dq_ + ch;
    const int* pos = posArr + b * Lq_ + s * SEGLEN;
    const float* pp = pprob + b * Lq_ + s * SEGLEN;
    float* sm = out_sm + (size_t)b * Lq_ * Dq_ + (size_t)s * SEGLEN * Dq_ + ch;
    float h = carryArr[((size_t)b * NSEG + s) * Dq_ + ch];
    for (int u = 0; u < SEGLEN; ++u) {
        float pv = pp[u];
        int t0 = pos[u];
        h = fmaf(1.f - pv, h, tb[(size_t)t0 * Dq_] * pv);
        sm[(size_t)u * Dq_] = h;
    }
}

// ---------------------------------------------------------------------------
__global__ __launch_bounds__(256) void upsample_kernel(const float* __restrict__ sm,
                                                       const int* __restrict__ cid,
                                                       float* __restrict__ up) {
    int r = blockIdx.x;
    int b = r >> 12;
    int c = cid[r];
    const float* src = sm + ((size_t)b * Lq_ + c) * Dq_;
    float* dst = up + (size_t)r * Dq_;
    int tid = threadIdx.x;
    *(float4*)&dst[tid * 8] = *(const float4*)&src[tid * 8];
    *(float4*)&dst[tid * 8 + 4] = *(const float4*)&src[tid * 8 + 4];
}

// ---------------------------------------------------------------------------
extern "C" void kernel_launch(void* const* d_in, const int* in_sizes, int n_in,
                              void* d_out, int out_size, void* d_ws, size_t ws_size,
                              hipStream_t stream) {
    const float* tokens = (const float*)d_in[0];
    const float* W = (const float*)d_in[1];
    const float* s = (const float*)d_in[2];

    float* out = (float*)d_out;
    float* out_sm = out;
    float* out_up = out + (size_t)Mq_ * Dq_;
    float* out_aux = out + 2 * (size_t)Mq_ * Dq_;

    // bf16 staging buffers live inside d_out (overwritten by final outputs later)
    unsigned short* Thi = (unsigned short*)out_up;                      // 64 MB
    unsigned short* Tlo = (unsigned short*)((char*)out_up + 67108864);  // 64 MB
    unsigned short* WhiT = (unsigned short*)out_sm;                     // 16 MB
    unsigned short* WloT = (unsigned short*)((char*)out_sm + 16777216); // 16 MB

    float* ws = (float*)d_ws;
    float* pa = ws;                              // 32*16384
    float* pkn = pa + (size_t)NTILES * Mq_;
    float* pcn = pkn + (size_t)NTILES * Mq_;
    float* probs = pcn + (size_t)NTILES * Mq_;   // 16384
    float* w = probs + Mq_;                      // 2048
    float* c0 = w + DQK_;                        // 4
    float* snorm = c0 + 4;                       // 4
    float* pprob = snorm + 4;                    // 16384
    int* posArr = (int*)(pprob + Mq_);           // 16384
    int* cid = posArr + Mq_;                     // 16384
    int* nch = cid + Mq_;                        // 8
    float* hseg = (float*)(nch + 8);             // 4*16*2048
    float* segGate = hseg + Bq_ * NSEG * Dq_;    // 64
    float* carryArr = segGate + 64;              // 4*16*2048

    split_kernel<<<2048, 256, 0, stream>>>(tokens, Thi, Tlo, Mq_ * Dq_ / 4);
    wsplitT_kernel<<<dim3(32, 64), 256, 0, stream>>>(W, WhiT, WloT);
    wqs_kernel<<<DQK_, 256, 0, stream>>>(W, s, w);
    l0_kernel<<<Bq_ + 1, 256, 0, stream>>>(tokens, s, w, c0, snorm);

    hipFuncSetAttribute(reinterpret_cast<const void*>(gemm_kernel),
                        hipFuncAttributeMaxDynamicSharedMemorySize, 73728);
    gemm_kernel<<<4096, 256, 73728, stream>>>(Thi, Tlo, WhiT, WloT, pa, pkn, pcn);

    rowstat_kernel<<<Mq_ / 256, 256, 0, stream>>>(pa, pkn, pcn, c0, snorm, probs);
    pack_kernel<<<Bq_, 256, 0, stream>>>(probs, posArr, pprob, cid, nch, out_aux);
    segend_kernel<<<dim3(8, NSEG, Bq_), 256, 0, stream>>>(tokens, posArr, pprob, hseg, segGate);
    carry_kernel<<<32, 256, 0, stream>>>(hseg, segGate, carryArr);
    scan3_kernel<<<dim3(8, NSEG, Bq_), 256, 0, stream>>>(tokens, posArr, pprob, carryArr, out_sm);
    upsample_kernel<<<Mq_, 256, 0, stream>>>(out_sm, cid, out_up);
}